// Round 2
// baseline (86.884 us; speedup 1.0000x reference)
//
#include <hip/hip_runtime.h>
#include <math.h>

namespace {

constexpr int NU    = 3;    // U
constexpr int DPN   = 128;  // DP
constexpr int TOPK  = 32;   // K
constexpr int NB    = 64;   // B
constexpr int NCAND = 119;  // sum_{r=0..31} floor(32/(r+1))

// One block (= one 64-lane wave) per batch row.
__global__ __launch_bounds__(64) void kron_topk_kernel(
    const float* __restrict__ z, const float* __restrict__ log_tau,
    float* __restrict__ out) {
  const int row  = blockIdx.x;
  const int lane = threadIdx.x;

  __shared__ float p[NU][DPN];      // softmax probabilities
  __shared__ float sval[NU][TOPK];  // per-factor top-32 values (sorted desc)
  __shared__ int   sidx[NU][TOPK];
  __shared__ float cval[DPN];       // stage candidates (119 used, rest pad)
  __shared__ int   cidx[DPN];
  __shared__ float aval[TOPK];      // running stage result (sorted desc)
  __shared__ int   aidx[TOPK];

  const float tau = expf(log_tau[0]);
  const float* zr = z + row * (NU * DPN);

  // ---- softmax for all 3 segments; each lane owns elements {lane, lane+64}
  float pv[NU][2];
  for (int u = 0; u < NU; ++u) {
    float x0 = zr[u * DPN + lane] / tau;
    float x1 = zr[u * DPN + lane + 64] / tau;

    float mm = fmaxf(x0, x1);
    for (int d = 32; d > 0; d >>= 1) mm = fmaxf(mm, __shfl_xor(mm, d));
    mm = __shfl(mm, 0);  // exact (max is order-insensitive)

    float e0 = expf(x0 - mm);
    float e1 = expf(x1 - mm);
    // Lane 0's butterfly partial-sum sequence == round-1's LDS tree
    // (red[i] += red[i+s], s=64..1), which matched the reference bit-exactly.
    float ss = e0 + e1;
    for (int d = 32; d > 0; d >>= 1) ss += __shfl_xor(ss, d);
    ss = __shfl(ss, 0);  // broadcast lane-0 value -> all lanes share one denom

    pv[u][0] = e0 / ss;
    pv[u][1] = e1 / ss;
    p[u][lane]      = pv[u][0];
    p[u][lane + 64] = pv[u][1];
  }
  __syncthreads();

  // ---- per-factor exact top-32 via rank-by-count (desc value, asc index)
  for (int u = 0; u < NU; ++u) {
    const float v0 = pv[u][0], v1 = pv[u][1];
    int r0 = 0, r1 = 0;
    for (int j = 0; j < DPN; ++j) {
      float w = p[u][j];  // LDS broadcast
      r0 += (w > v0) || (w == v0 && j < lane);
      r1 += (w > v1) || (w == v1 && j < lane + 64);
    }
    if (r0 < TOPK) { sval[u][r0] = v0; sidx[u][r0] = lane; }
    if (r1 < TOPK) { sval[u][r1] = v1; sidx[u][r1] = lane + 64; }
  }
  __syncthreads();

  // ---- stage chain: A := top32(p0); A := top32(A x p_u) for u = 1,2
  if (lane < TOPK) { aval[lane] = sval[0][lane]; aidx[lane] = sidx[0][lane]; }
  __syncthreads();

  for (int u = 1; u < NU; ++u) {
    // Only pairs (r,s) with (r+1)(s+1) <= 32 can reach the product top-32
    // when both lists are sorted descending.
    for (int c = lane; c < DPN; c += 64) {
      float v = -1.0f;           // pad ranks last (all probs > 0)
      int idx = 0x7fffffff;
      if (c < NCAND) {
        int t = c, r = 0;
        while (true) {
          int cnt = TOPK / (r + 1);
          if (t < cnt) break;
          t -= cnt;
          ++r;
        }
        v   = aval[r] * sval[u][t];        // f32 rounding matches reference
        idx = aidx[r] * DPN + sidx[u][t];  // flat index growth: i*DP + j
      }
      cval[c] = v;
      cidx[c] = idx;
    }
    __syncthreads();

    const float v0 = cval[lane];
    const float v1 = cval[lane + 64];
    const int   i0 = cidx[lane];
    const int   i1 = cidx[lane + 64];
    int r0 = 0, r1 = 0;
    for (int j = 0; j < DPN; ++j) {
      float w = cval[j];
      int  wi = cidx[j];
      r0 += (w > v0) || (w == v0 && wi < i0);
      r1 += (w > v1) || (w == v1 && wi < i1);
    }
    __syncthreads();  // all reads of aval/cval done before rewrite
    if (r0 < TOPK) { aval[r0] = v0; aidx[r0] = i0; }
    if (r1 < TOPK) { aval[r1] = v1; aidx[r1] = i1; }
    __syncthreads();
  }

  // ---- write: indices chunk (as float values), then weights chunk
  if (lane < TOPK) {
    out[row * TOPK + lane]             = (float)aidx[lane];
    out[NB * TOPK + row * TOPK + lane] = aval[lane];
  }
}

}  // namespace

extern "C" void kernel_launch(void* const* d_in, const int* in_sizes, int n_in,
                              void* d_out, int out_size, void* d_ws, size_t ws_size,
                              hipStream_t stream) {
  const float* z       = (const float*)d_in[0];
  const float* log_tau = (const float*)d_in[1];
  float* out           = (float*)d_out;
  hipLaunchKernelGGL(kron_topk_kernel, dim3(NB), dim3(64), 0, stream,
                     z, log_tau, out);
}

// Round 4
// 75.295 us; speedup vs baseline: 1.1539x; 1.1539x over previous
//
#include <hip/hip_runtime.h>
#include <math.h>

namespace {

constexpr int NU    = 3;    // U
constexpr int DPN   = 128;  // DP
constexpr int TOPK  = 32;   // K
constexpr int NB    = 64;   // B
constexpr int NCAND = 119;  // sum_{r=0..31} floor(32/(r+1))

// One block (2 waves, 128 threads) per batch row.
__global__ __launch_bounds__(DPN) void kron_topk_kernel(
    const float* __restrict__ z, const float* __restrict__ log_tau,
    float* __restrict__ out) {
  const int row = blockIdx.x;
  const int tid = threadIdx.x;

  __shared__ __align__(16) float p[NU][DPN];    // softmax probabilities
  __shared__ __align__(16) float red[NU][DPN];  // fused reduction scratch
  __shared__ float sval[NU][TOPK];              // per-factor top-32 (desc)
  __shared__ int   sidx[NU][TOPK];
  __shared__ __align__(16) float cval[DPN];     // stage candidates (119 + pad)
  __shared__ __align__(16) int   cidx[DPN];
  __shared__ float aval[TOPK];                  // running stage result
  __shared__ int   aidx[TOPK];

  // ---- hoisted global loads (independent; overlap their latency)
  const float* zr = z + row * (NU * DPN);
  float x[NU];
#pragma unroll
  for (int u = 0; u < NU; ++u) x[u] = zr[u * DPN + tid];
  const float tau = expf(log_tau[0]);

  // ---- static candidate map (r,s) for tid<NCAND: (r+1)(s+1) <= 32
  int rmap = 0, smap = 0;
  const bool cact = tid < NCAND;
  if (cact) {
    int t = tid, r = 0;
    while (true) {
      int cnt = TOPK / (r + 1);
      if (t < cnt) break;
      t -= cnt;
      ++r;
    }
    rmap = r;
    smap = t;
  }

  // ---- fused 3-way softmax (identical per-u arithmetic to verified tree)
  if (tau != 1.0f) {       // uniform branch; x/1.0f == x bitwise
#pragma unroll
    for (int u = 0; u < NU; ++u) x[u] /= tau;
  }
#pragma unroll
  for (int u = 0; u < NU; ++u) red[u][tid] = x[u];
  __syncthreads();
  for (int s = DPN / 2; s > 0; s >>= 1) {
    if (tid < s) {
#pragma unroll
      for (int u = 0; u < NU; ++u)
        red[u][tid] = fmaxf(red[u][tid], red[u][tid + s]);
    }
    __syncthreads();
  }
  float e[NU];
#pragma unroll
  for (int u = 0; u < NU; ++u) e[u] = expf(x[u] - red[u][0]);
  __syncthreads();
#pragma unroll
  for (int u = 0; u < NU; ++u) red[u][tid] = e[u];
  __syncthreads();
  for (int s = DPN / 2; s > 0; s >>= 1) {
    if (tid < s) {
#pragma unroll
      for (int u = 0; u < NU; ++u) red[u][tid] += red[u][tid + s];
    }
    __syncthreads();
  }
  float pv[NU];
#pragma unroll
  for (int u = 0; u < NU; ++u) {
    pv[u] = e[u] / red[u][0];
    p[u][tid] = pv[u];
  }
  __syncthreads();

  // ---- per-factor exact top-32 via rank-by-count, fused over u, b128 reads
  {
    int rk[NU] = {0, 0, 0};
    const float4* p4_0 = reinterpret_cast<const float4*>(&p[0][0]);
    const float4* p4_1 = reinterpret_cast<const float4*>(&p[1][0]);
    const float4* p4_2 = reinterpret_cast<const float4*>(&p[2][0]);
#pragma unroll 8
    for (int jj = 0; jj < DPN / 4; ++jj) {
      float4 w0 = p4_0[jj];
      float4 w1 = p4_1[jj];
      float4 w2 = p4_2[jj];
      const float* w0e = &w0.x;
      const float* w1e = &w1.x;
      const float* w2e = &w2.x;
#pragma unroll
      for (int ee = 0; ee < 4; ++ee) {
        int j = 4 * jj + ee;
        rk[0] += (w0e[ee] > pv[0]) || (w0e[ee] == pv[0] && j < tid);
        rk[1] += (w1e[ee] > pv[1]) || (w1e[ee] == pv[1] && j < tid);
        rk[2] += (w2e[ee] > pv[2]) || (w2e[ee] == pv[2] && j < tid);
      }
    }
#pragma unroll
    for (int u = 0; u < NU; ++u)
      if (rk[u] < TOPK) { sval[u][rk[u]] = pv[u]; sidx[u][rk[u]] = tid; }
  }
  __syncthreads();

  // ---- stage chain: A := top32(p0); A := top32(A x p_u) for u = 1,2
  if (tid < TOPK) { aval[tid] = sval[0][tid]; aidx[tid] = sidx[0][tid]; }
  __syncthreads();

  for (int u = 1; u < NU; ++u) {
    float v = -1.0f;            // pad ranks last (all probs > 0)
    int idx = 0x7fffffff;
    if (cact) {
      v   = aval[rmap] * sval[u][smap];      // f32 rounding matches reference
      idx = aidx[rmap] * DPN + sidx[u][smap];
    }
    cval[tid] = v;
    cidx[tid] = idx;
    __syncthreads();

    int rank = 0;
    const float4* cv4 = reinterpret_cast<const float4*>(cval);
    const int4*   ci4 = reinterpret_cast<const int4*>(cidx);
#pragma unroll 8
    for (int jj = 0; jj < DPN / 4; ++jj) {
      float4 w4 = cv4[jj];
      int4   i4 = ci4[jj];
      const float* we = &w4.x;
      const int*   ie = &i4.x;
#pragma unroll
      for (int ee = 0; ee < 4; ++ee)
        rank += (we[ee] > v) || (we[ee] == v && ie[ee] < idx);
    }
    __syncthreads();  // all reads of aval/cval done before rewrite
    if (rank < TOPK) { aval[rank] = v; aidx[rank] = idx; }
    __syncthreads();
  }

  // ---- write: indices chunk (as float values), then weights chunk
  if (tid < TOPK) {
    out[row * TOPK + tid]              = (float)aidx[tid];
    out[NB * TOPK + row * TOPK + tid]  = aval[tid];
  }
}

}  // namespace

extern "C" void kernel_launch(void* const* d_in, const int* in_sizes, int n_in,
                              void* d_out, int out_size, void* d_ws, size_t ws_size,
                              hipStream_t stream) {
  const float* z       = (const float*)d_in[0];
  const float* log_tau = (const float*)d_in[1];
  float* out           = (float*)d_out;
  hipLaunchKernelGGL(kron_topk_kernel, dim3(NB), dim3(DPN), 0, stream,
                     z, log_tau, out);
}